// Round 2
// baseline (536.282 us; speedup 1.0000x reference)
//
#include <hip/hip_runtime.h>
#include <stdint.h>

typedef __bf16 bf16_t;
typedef __bf16 bf16x8 __attribute__((ext_vector_type(8)));
typedef __bf16 bf16x4 __attribute__((ext_vector_type(4)));
typedef float  f32x4  __attribute__((ext_vector_type(4)));

#define L2E 1.44269504088896340736f
#define LAMBDA_INIT 0.7836057665316245f
#define ONE_MINUS_LAMBDA_INIT 0.2163942334683755f

// ---------------------------------------------------------------- helpers
__device__ __forceinline__ void gload_lds16(const void* g, void* l) {
  __builtin_amdgcn_global_load_lds(
      (const __attribute__((address_space(1))) char*)(uintptr_t)g,
      (__attribute__((address_space(3))) char*)(uintptr_t)l, 16, 0, 0);
}

__device__ __forceinline__ f32x4 mfma_bf16(bf16x8 a, bf16x8 b, f32x4 c) {
  return __builtin_amdgcn_mfma_f32_16x16x32_bf16(a, b, c, 0, 0, 0);
}

// ---------------------------------------------------------------- conversions
__global__ __launch_bounds__(256) void cvt_bf16(const float* __restrict__ in,
                                                bf16_t* __restrict__ out) {
  const size_t idx = ((size_t)blockIdx.x * 256 + threadIdx.x) * 8;
  float4 a = *(const float4*)(in + idx);
  float4 c = *(const float4*)(in + idx + 4);
  bf16x8 v;
  v[0] = (bf16_t)a.x; v[1] = (bf16_t)a.y; v[2] = (bf16_t)a.z; v[3] = (bf16_t)a.w;
  v[4] = (bf16_t)c.x; v[5] = (bf16_t)c.y; v[6] = (bf16_t)c.z; v[7] = (bf16_t)c.w;
  *(bf16x8*)(out + idx) = v;
}

// W [2048,2048] f32 -> WT [2048,2048] bf16 with WT[n][k] = W[k][n]*scale
__global__ __launch_bounds__(256) void cvt_wT(const float* __restrict__ W,
                                              bf16_t* __restrict__ WT, float scale) {
  __shared__ float t[64][65];
  const int k0 = blockIdx.x * 64, n0 = blockIdx.y * 64;
  const int r = threadIdx.x >> 2, cg = threadIdx.x & 3;
#pragma unroll
  for (int q = 0; q < 4; ++q) {
    float4 v = *(const float4*)(W + (size_t)(k0 + r) * 2048 + n0 + cg * 16 + q * 4);
    t[r][cg * 16 + q * 4 + 0] = v.x;
    t[r][cg * 16 + q * 4 + 1] = v.y;
    t[r][cg * 16 + q * 4 + 2] = v.z;
    t[r][cg * 16 + q * 4 + 3] = v.w;
  }
  __syncthreads();
  bf16x8 o0, o1;
#pragma unroll
  for (int j = 0; j < 8; ++j) o0[j] = (bf16_t)(t[cg * 16 + j][r] * scale);
#pragma unroll
  for (int j = 0; j < 8; ++j) o1[j] = (bf16_t)(t[cg * 16 + 8 + j][r] * scale);
  bf16_t* dst = WT + (size_t)(n0 + r) * 2048 + k0 + cg * 16;
  *(bf16x8*)dst = o0;
  *(bf16x8*)(dst + 8) = o1;
}

__global__ void lam_kernel(const float* lq1, const float* lk1,
                           const float* lq2, const float* lk2, float* out) {
  const int l = threadIdx.x;  // 64 threads
  float p1 = lq1[l] * lk1[l];
  float p2 = lq2[l] * lk2[l];
#pragma unroll
  for (int d = 1; d < 64; d <<= 1) {
    p1 += __shfl_xor(p1, d);
    p2 += __shfl_xor(p2, d);
  }
  if (l == 0) *out = expf(p1) - expf(p2) + LAMBDA_INIT;
}

// ---------------------------------------------------------------- GEMM
// C[M=4096, N=2048] = A[4096,2048] @ B, B given as Bt[N][K] (bf16).
// OUTMODE 0: bf16 C row-major; 1: bf16 C transposed ([N][M], for V^T);
// 2: f32 C row-major.
template <int OUTMODE>
__global__ __launch_bounds__(256, 2) void gemm_bt(const bf16_t* __restrict__ A,
                                                  const bf16_t* __restrict__ Bt,
                                                  void* __restrict__ Cv) {
  __shared__ __align__(16) bf16_t As[128 * 64];
  __shared__ __align__(16) bf16_t Bs[128 * 64];
  const int tid = threadIdx.x;
  const int w = tid >> 6, lane = tid & 63;
  const int wr = w >> 1, wc = w & 1;
  const int lm = lane >> 4, ln = lane & 15;
  const int m0 = blockIdx.x * 128, n0 = blockIdx.y * 128;

  const f32x4 vzero = {0.f, 0.f, 0.f, 0.f};
  f32x4 acc[4][4];
#pragma unroll
  for (int m = 0; m < 4; ++m)
#pragma unroll
    for (int n = 0; n < 4; ++n) acc[m][n] = vzero;

  for (int k0 = 0; k0 < 2048; k0 += 64) {
    __syncthreads();
#pragma unroll
    for (int j = 0; j < 4; ++j) {
      const int inst = w * 4 + j;
      const int row = inst * 8 + (lane >> 3);              // tile row (RS=128B)
      const int cb = ((lane & 7) * 16) ^ ((row & 7) << 4); // pre-swizzled source col
      gload_lds16(A + (size_t)(m0 + row) * 2048 + k0 + (cb >> 1),
                  (char*)As + inst * 1024);
      gload_lds16(Bt + (size_t)(n0 + row) * 2048 + k0 + (cb >> 1),
                  (char*)Bs + inst * 1024);
    }
    asm volatile("s_waitcnt vmcnt(0)" ::: "memory");
    __syncthreads();

#pragma unroll
    for (int kc = 0; kc < 2; ++kc) {
      bf16x8 af[4], bfr[4];
#pragma unroll
      for (int m = 0; m < 4; ++m) {
        const int row = wr * 64 + m * 16 + ln;
        int off = row * 128 + kc * 64 + lm * 16;
        off ^= (row & 7) << 4;
        af[m] = *(const bf16x8*)((const char*)As + off);
      }
#pragma unroll
      for (int n = 0; n < 4; ++n) {
        const int row = wc * 64 + n * 16 + ln;
        int off = row * 128 + kc * 64 + lm * 16;
        off ^= (row & 7) << 4;
        bfr[n] = *(const bf16x8*)((const char*)Bs + off);
      }
#pragma unroll
      for (int m = 0; m < 4; ++m)
#pragma unroll
        for (int n = 0; n < 4; ++n) acc[m][n] = mfma_bf16(af[m], bfr[n], acc[m][n]);
    }
  }

  if (OUTMODE == 0) {
    bf16_t* C = (bf16_t*)Cv;
#pragma unroll
    for (int m = 0; m < 4; ++m)
#pragma unroll
      for (int n = 0; n < 4; ++n)
#pragma unroll
        for (int r = 0; r < 4; ++r) {
          const size_t grow = m0 + wr * 64 + m * 16 + lm * 4 + r;
          const int gcol = n0 + wc * 64 + n * 16 + ln;
          C[grow * 2048 + gcol] = (bf16_t)acc[m][n][r];
        }
  } else if (OUTMODE == 1) {
    bf16_t* C = (bf16_t*)Cv;  // [2048][4096]
#pragma unroll
    for (int m = 0; m < 4; ++m)
#pragma unroll
      for (int n = 0; n < 4; ++n) {
        const size_t gcol = n0 + wc * 64 + n * 16 + ln;
        const int growb = m0 + wr * 64 + m * 16 + lm * 4;
        bf16x4 v;
#pragma unroll
        for (int r = 0; r < 4; ++r) v[r] = (bf16_t)acc[m][n][r];
        *(bf16x4*)(C + gcol * 4096 + growb) = v;
      }
  } else {
    float* C = (float*)Cv;
#pragma unroll
    for (int m = 0; m < 4; ++m)
#pragma unroll
      for (int n = 0; n < 4; ++n)
#pragma unroll
        for (int r = 0; r < 4; ++r) {
          const size_t grow = m0 + wr * 64 + m * 16 + lm * 4 + r;
          const int gcol = n0 + wc * 64 + n * 16 + ln;
          C[grow * 2048 + gcol] = acc[m][n][r];
        }
  }
}

// ---------------------------------------------------------------- flash diff-attn
// Q,K: [4096, 2048] bf16 (col = subhead*64+hd); Vt: [2048, 4096] bf16 (Vt[d][bt]).
// attnb: [4096, 2048] bf16 output (col = h*128 + d).
// Q was pre-scaled by HD^-0.5 * log2(e), so P = exp2(S) directly.
// No online max: scores are bounded (~N(0,0.7)), exp(S) safe in f32.
__global__ __launch_bounds__(256, 3) void flash_diff(const bf16_t* __restrict__ Q,
                                                     const bf16_t* __restrict__ K,
                                                     const bf16_t* __restrict__ Vt,
                                                     bf16_t* __restrict__ attnb,
                                                     const float* __restrict__ lamP) {
  __shared__ __align__(16) char smem[49152];
  bf16_t* Qs = (bf16_t*)smem;            // [64][128], only used before K-loop
  bf16_t* Ks = (bf16_t*)(smem + 16384);  // [64][128]
  bf16_t* Vs = (bf16_t*)(smem + 32768);  // [128][64]
  bf16_t* Ps = (bf16_t*)smem;            // overlays Qs: 4 waves x 2 sub x [16][64]

  const int tid = threadIdx.x;
  const int w = tid >> 6, lane = tid & 63;
  const int lm = lane >> 4, ln = lane & 15;
  const int qt = (int)gridDim.x - 1 - (int)blockIdx.x;  // longest blocks first
  const int h = blockIdx.y, b = blockIdx.z;
  const int q0 = qt * 64;
  const size_t bt0 = (size_t)b * 2048;
  const float lam = *lamP;

  // stage Q tile [64 rows][128 cols] (RS=256B)
#pragma unroll
  for (int j = 0; j < 4; ++j) {
    const int inst = w * 4 + j;
    const int row = inst * 4 + (lane >> 4);
    const int cb = ((lane & 15) * 16) ^ ((row & 7) << 4);
    gload_lds16(Q + (bt0 + q0 + row) * 2048 + h * 128 + (cb >> 1),
                (char*)Qs + inst * 1024);
  }
  asm volatile("s_waitcnt vmcnt(0)" ::: "memory");
  __syncthreads();

  bf16x8 qf[2][2];
#pragma unroll
  for (int s = 0; s < 2; ++s)
#pragma unroll
    for (int kc = 0; kc < 2; ++kc) {
      const int row = w * 16 + ln;
      int off = row * 256 + s * 128 + kc * 64 + lm * 16;
      off ^= (row & 7) << 4;
      qf[s][kc] = *(const bf16x8*)((const char*)Qs + off);
    }
  // NOTE: Qs is dead after this point; Ps overlays it. The kt=0 loop-top
  // __syncthreads() guarantees every wave's qf ds_reads drained (compiler
  // emits lgkmcnt(0) before s_barrier) before any wave writes Ps.

  const f32x4 vzero = {0.f, 0.f, 0.f, 0.f};
  f32x4 acc[2][8];
  float lsum[2][4];
#pragma unroll
  for (int s = 0; s < 2; ++s) {
#pragma unroll
    for (int n = 0; n < 8; ++n) acc[s][n] = vzero;
#pragma unroll
    for (int r = 0; r < 4; ++r) lsum[s][r] = 0.f;
  }

  for (int kt = 0; kt <= qt; ++kt) {
    const int k0 = kt * 64;
    __syncthreads();
#pragma unroll
    for (int j = 0; j < 4; ++j) {
      const int inst = w * 4 + j;
      {  // K tile [64][128], RS=256B
        const int row = inst * 4 + (lane >> 4);
        const int cb = ((lane & 15) * 16) ^ ((row & 7) << 4);
        gload_lds16(K + (bt0 + k0 + row) * 2048 + h * 128 + (cb >> 1),
                    (char*)Ks + inst * 1024);
      }
      {  // Vt tile [128][64], RS=128B
        const int row = inst * 8 + (lane >> 3);
        const int cb = ((lane & 7) * 16) ^ ((row & 7) << 4);
        gload_lds16(Vt + (size_t)(h * 128 + row) * 4096 + bt0 + k0 + (cb >> 1),
                    (char*)Vs + inst * 1024);
      }
    }
    asm volatile("s_waitcnt vmcnt(0)" ::: "memory");
    __syncthreads();

#pragma unroll
    for (int s = 0; s < 2; ++s) {
      f32x4 sa[4];
#pragma unroll
      for (int n = 0; n < 4; ++n) sa[n] = vzero;
#pragma unroll
      for (int kc = 0; kc < 2; ++kc) {
#pragma unroll
        for (int n = 0; n < 4; ++n) {
          const int row = n * 16 + ln;
          int off = row * 256 + s * 128 + kc * 64 + lm * 16;
          off ^= (row & 7) << 4;
          bf16x8 kf = *(const bf16x8*)((const char*)Ks + off);
          sa[n] = mfma_bf16(qf[s][kc], kf, sa[n]);
        }
      }
      if (kt == qt) {  // causal mask within diagonal tile (k0 == q0)
#pragma unroll
        for (int n = 0; n < 4; ++n)
#pragma unroll
          for (int r = 0; r < 4; ++r) {
            const int kg = n * 16 + ln;
            const int qg = w * 16 + lm * 4 + r;
            if (kg > qg) sa[n][r] = -1e30f;
          }
      }
      // P = exp2(S) (log2e folded into Q); per-lane partial row sums only.
      bf16_t* pbase = Ps + (w * 2 + s) * 1024;
#pragma unroll
      for (int r = 0; r < 4; ++r) {
        float ps = 0.f;
#pragma unroll
        for (int n = 0; n < 4; ++n) {
          const float p = exp2f(sa[n][r]);
          sa[n][r] = p;
          ps += p;
        }
        lsum[s][r] += ps;
      }
      // write P (bf16) to per-wave scratch [16][64], RS=128B, swizzled
#pragma unroll
      for (int n = 0; n < 4; ++n)
#pragma unroll
        for (int r = 0; r < 4; ++r) {
          const int row = lm * 4 + r;
          int off = row * 128 + (n * 16 + ln) * 2;
          off ^= (row & 7) << 4;
          *(bf16_t*)((char*)pbase + off) = (bf16_t)sa[n][r];
        }
    }

    // PV for both sub-heads, V fragments read once
#pragma unroll
    for (int kc = 0; kc < 2; ++kc) {
      bf16x8 pf[2];
#pragma unroll
      for (int s = 0; s < 2; ++s) {
        int off = ln * 128 + kc * 64 + lm * 16;
        off ^= (ln & 7) << 4;
        pf[s] = *(const bf16x8*)((const char*)(Ps + (w * 2 + s) * 1024) + off);
      }
#pragma unroll
      for (int n = 0; n < 8; ++n) {
        const int row = n * 16 + ln;
        int off = row * 128 + kc * 64 + lm * 16;
        off ^= (row & 7) << 4;
        bf16x8 vf = *(const bf16x8*)((const char*)Vs + off);
        acc[0][n] = mfma_bf16(pf[0], vf, acc[0][n]);
        acc[1][n] = mfma_bf16(pf[1], vf, acc[1][n]);
      }
    }
  }

  // epilogue: finish row sums (4 shuffles, once), combine, RMSNorm(128), store
#pragma unroll
  for (int r = 0; r < 4; ++r) {
    float l0 = lsum[0][r], l1 = lsum[1][r];
#pragma unroll
    for (int d = 1; d < 16; d <<= 1) {
      l0 += __shfl_xor(l0, d);
      l1 += __shfl_xor(l1, d);
    }
    const float rl0 = 1.0f / l0;
    const float rl1 = 1.0f / l1;
    float o[8];
    float ss = 0.f;
#pragma unroll
    for (int n = 0; n < 8; ++n) {
      const float v = acc[0][n][r] * rl0 - lam * (acc[1][n][r] * rl1);
      o[n] = v;
      ss += v * v;
    }
    ss += __shfl_xor(ss, 1);
    ss += __shfl_xor(ss, 2);
    ss += __shfl_xor(ss, 4);
    ss += __shfl_xor(ss, 8);
    const float sc = rsqrtf(ss * (1.0f / 128.f) + 1e-5f) * ONE_MINUS_LAMBDA_INIT;
    const size_t grow = bt0 + q0 + w * 16 + lm * 4 + r;
#pragma unroll
    for (int n = 0; n < 8; ++n)
      attnb[grow * 2048 + h * 128 + n * 16 + ln] = (bf16_t)(o[n] * sc);
  }
}

// ---------------------------------------------------------------- launch
extern "C" void kernel_launch(void* const* d_in, const int* in_sizes, int n_in,
                              void* d_out, int out_size, void* d_ws, size_t ws_size,
                              hipStream_t stream) {
  const float* x   = (const float*)d_in[0];
  const float* Wq  = (const float*)d_in[1];
  const float* Wk  = (const float*)d_in[2];
  const float* Wv  = (const float*)d_in[3];
  const float* Wo  = (const float*)d_in[4];
  const float* lq1 = (const float*)d_in[5];
  const float* lk1 = (const float*)d_in[6];
  const float* lq2 = (const float*)d_in[7];
  const float* lk2 = (const float*)d_in[8];

  char* ws = (char*)d_ws;
  // layout (bytes)
  bf16_t* xb    = (bf16_t*)(ws + 0);                 // 16 MB  [4096,2048]
  bf16_t* wqT   = (bf16_t*)(ws + 16777216);          // 8 MB
  bf16_t* wkT   = (bf16_t*)(ws + 25165824);          // 8 MB
  bf16_t* wvT   = (bf16_t*)(ws + 33554432);          // 8 MB
  bf16_t* woT   = (bf16_t*)(ws + 41943040);          // 8 MB
  bf16_t* Qb    = (bf16_t*)(ws + 50331648);          // 16 MB
  bf16_t* Kb    = (bf16_t*)(ws + 67108864);          // 16 MB
  bf16_t* Vtb   = (bf16_t*)(ws + 16777216);          // 16 MB (aliases wqT+wkT; used after their GEMMs)
  bf16_t* attnb = (bf16_t*)(ws + 0);                 // 16 MB (aliases xb; used after V GEMM)
  float*  lamP  = (float*)(ws + 83886080);

  cvt_bf16<<<4096, 256, 0, stream>>>(x, xb);
  // fold HD^-0.5 * log2(e) into Q so P = exp2(S)
  cvt_wT<<<dim3(32, 32), 256, 0, stream>>>(Wq, wqT, 0.125f * L2E);
  cvt_wT<<<dim3(32, 32), 256, 0, stream>>>(Wk, wkT, 1.0f);
  cvt_wT<<<dim3(32, 32), 256, 0, stream>>>(Wv, wvT, 1.0f);
  cvt_wT<<<dim3(32, 32), 256, 0, stream>>>(Wo, woT, 1.0f);
  lam_kernel<<<1, 64, 0, stream>>>(lq1, lk1, lq2, lk2, lamP);

  gemm_bt<0><<<dim3(32, 16), 256, 0, stream>>>(xb, wqT, (void*)Qb);
  gemm_bt<0><<<dim3(32, 16), 256, 0, stream>>>(xb, wkT, (void*)Kb);
  gemm_bt<1><<<dim3(32, 16), 256, 0, stream>>>(xb, wvT, (void*)Vtb);  // V^T out

  flash_diff<<<dim3(32, 16, 2), 256, 0, stream>>>(Qb, Kb, Vtb, attnb, lamP);

  gemm_bt<2><<<dim3(32, 16), 256, 0, stream>>>(attnb, woT, d_out);
}

// Round 3
// 287.861 us; speedup vs baseline: 1.8630x; 1.8630x over previous
//
#include <hip/hip_runtime.h>
#include <stdint.h>

typedef __bf16 bf16_t;
typedef __bf16 bf16x8 __attribute__((ext_vector_type(8)));
typedef __bf16 bf16x4 __attribute__((ext_vector_type(4)));
typedef float  f32x4  __attribute__((ext_vector_type(4)));

#define L2E 1.44269504088896340736f
#define LAMBDA_INIT 0.7836057665316245f
#define ONE_MINUS_LAMBDA_INIT 0.2163942334683755f

// ---------------------------------------------------------------- helpers
__device__ __forceinline__ void gload_lds16(const void* g, void* l) {
  __builtin_amdgcn_global_load_lds(
      (const __attribute__((address_space(1))) char*)(uintptr_t)g,
      (__attribute__((address_space(3))) char*)(uintptr_t)l, 16, 0, 0);
}

__device__ __forceinline__ f32x4 mfma_bf16(bf16x8 a, bf16x8 b, f32x4 c) {
  return __builtin_amdgcn_mfma_f32_16x16x32_bf16(a, b, c, 0, 0, 0);
}

// ---------------------------------------------------------------- conversions
__global__ __launch_bounds__(256) void cvt_bf16(const float* __restrict__ in,
                                                bf16_t* __restrict__ out) {
  const size_t idx = ((size_t)blockIdx.x * 256 + threadIdx.x) * 8;
  float4 a = *(const float4*)(in + idx);
  float4 c = *(const float4*)(in + idx + 4);
  bf16x8 v;
  v[0] = (bf16_t)a.x; v[1] = (bf16_t)a.y; v[2] = (bf16_t)a.z; v[3] = (bf16_t)a.w;
  v[4] = (bf16_t)c.x; v[5] = (bf16_t)c.y; v[6] = (bf16_t)c.z; v[7] = (bf16_t)c.w;
  *(bf16x8*)(out + idx) = v;
}

// W [2048,2048] f32 -> WT [2048,2048] bf16 with WT[n][k] = W[k][n]*scale
__global__ __launch_bounds__(256) void cvt_wT(const float* __restrict__ W,
                                              bf16_t* __restrict__ WT, float scale) {
  __shared__ float t[64][65];
  const int k0 = blockIdx.x * 64, n0 = blockIdx.y * 64;
  const int r = threadIdx.x >> 2, cg = threadIdx.x & 3;
#pragma unroll
  for (int q = 0; q < 4; ++q) {
    float4 v = *(const float4*)(W + (size_t)(k0 + r) * 2048 + n0 + cg * 16 + q * 4);
    t[r][cg * 16 + q * 4 + 0] = v.x;
    t[r][cg * 16 + q * 4 + 1] = v.y;
    t[r][cg * 16 + q * 4 + 2] = v.z;
    t[r][cg * 16 + q * 4 + 3] = v.w;
  }
  __syncthreads();
  bf16x8 o0, o1;
#pragma unroll
  for (int j = 0; j < 8; ++j) o0[j] = (bf16_t)(t[cg * 16 + j][r] * scale);
#pragma unroll
  for (int j = 0; j < 8; ++j) o1[j] = (bf16_t)(t[cg * 16 + 8 + j][r] * scale);
  bf16_t* dst = WT + (size_t)(n0 + r) * 2048 + k0 + cg * 16;
  *(bf16x8*)dst = o0;
  *(bf16x8*)(dst + 8) = o1;
}

__global__ void lam_kernel(const float* lq1, const float* lk1,
                           const float* lq2, const float* lk2, float* out) {
  const int l = threadIdx.x;  // 64 threads
  float p1 = lq1[l] * lk1[l];
  float p2 = lq2[l] * lk2[l];
#pragma unroll
  for (int d = 1; d < 64; d <<= 1) {
    p1 += __shfl_xor(p1, d);
    p2 += __shfl_xor(p2, d);
  }
  if (l == 0) *out = expf(p1) - expf(p2) + LAMBDA_INIT;
}

// ---------------------------------------------------------------- GEMM
// C[M=4096, N=2048] = A[4096,2048] @ B, B given as Bt[N][K] (bf16).
// OUTMODE 0: bf16 C row-major; 1: bf16 C transposed ([N][M], for V^T);
// 2: f32 C row-major.
template <int OUTMODE>
__global__ __launch_bounds__(256, 2) void gemm_bt(const bf16_t* __restrict__ A,
                                                  const bf16_t* __restrict__ Bt,
                                                  void* __restrict__ Cv) {
  __shared__ __align__(16) bf16_t As[128 * 64];
  __shared__ __align__(16) bf16_t Bs[128 * 64];
  const int tid = threadIdx.x;
  const int w = tid >> 6, lane = tid & 63;
  const int wr = w >> 1, wc = w & 1;
  const int lm = lane >> 4, ln = lane & 15;
  // bijective XCD swizzle (T1): 512 blocks, 8 XCDs, 64 per XCD contiguous
  const int flat = (int)blockIdx.y * (int)gridDim.x + (int)blockIdx.x;
  const int swz = (flat & 7) * 64 + (flat >> 3);
  const int m0 = (swz & 31) * 128, n0 = (swz >> 5) * 128;

  const f32x4 vzero = {0.f, 0.f, 0.f, 0.f};
  f32x4 acc[4][4];
#pragma unroll
  for (int m = 0; m < 4; ++m)
#pragma unroll
    for (int n = 0; n < 4; ++n) acc[m][n] = vzero;

  for (int k0 = 0; k0 < 2048; k0 += 64) {
    __syncthreads();
#pragma unroll
    for (int j = 0; j < 4; ++j) {
      const int inst = w * 4 + j;
      const int row = inst * 8 + (lane >> 3);              // tile row (RS=128B)
      const int cb = ((lane & 7) * 16) ^ ((row & 7) << 4); // pre-swizzled source col
      gload_lds16(A + (size_t)(m0 + row) * 2048 + k0 + (cb >> 1),
                  (char*)As + inst * 1024);
      gload_lds16(Bt + (size_t)(n0 + row) * 2048 + k0 + (cb >> 1),
                  (char*)Bs + inst * 1024);
    }
    asm volatile("s_waitcnt vmcnt(0)" ::: "memory");
    __syncthreads();

#pragma unroll
    for (int kc = 0; kc < 2; ++kc) {
      bf16x8 af[4], bfr[4];
#pragma unroll
      for (int m = 0; m < 4; ++m) {
        const int row = wr * 64 + m * 16 + ln;
        int off = row * 128 + kc * 64 + lm * 16;
        off ^= (row & 7) << 4;
        af[m] = *(const bf16x8*)((const char*)As + off);
      }
#pragma unroll
      for (int n = 0; n < 4; ++n) {
        const int row = wc * 64 + n * 16 + ln;
        int off = row * 128 + kc * 64 + lm * 16;
        off ^= (row & 7) << 4;
        bfr[n] = *(const bf16x8*)((const char*)Bs + off);
      }
      __builtin_amdgcn_s_setprio(1);
#pragma unroll
      for (int m = 0; m < 4; ++m)
#pragma unroll
        for (int n = 0; n < 4; ++n) acc[m][n] = mfma_bf16(af[m], bfr[n], acc[m][n]);
      __builtin_amdgcn_s_setprio(0);
    }
  }

  if (OUTMODE == 0) {
    bf16_t* C = (bf16_t*)Cv;
#pragma unroll
    for (int m = 0; m < 4; ++m)
#pragma unroll
      for (int n = 0; n < 4; ++n)
#pragma unroll
        for (int r = 0; r < 4; ++r) {
          const size_t grow = m0 + wr * 64 + m * 16 + lm * 4 + r;
          const int gcol = n0 + wc * 64 + n * 16 + ln;
          C[grow * 2048 + gcol] = (bf16_t)acc[m][n][r];
        }
  } else if (OUTMODE == 1) {
    bf16_t* C = (bf16_t*)Cv;  // [2048][4096]
#pragma unroll
    for (int m = 0; m < 4; ++m)
#pragma unroll
      for (int n = 0; n < 4; ++n) {
        const size_t gcol = n0 + wc * 64 + n * 16 + ln;
        const int growb = m0 + wr * 64 + m * 16 + lm * 4;
        bf16x4 v;
#pragma unroll
        for (int r = 0; r < 4; ++r) v[r] = (bf16_t)acc[m][n][r];
        *(bf16x4*)(C + gcol * 4096 + growb) = v;
      }
  } else {
    float* C = (float*)Cv;
#pragma unroll
    for (int m = 0; m < 4; ++m)
#pragma unroll
      for (int n = 0; n < 4; ++n)
#pragma unroll
        for (int r = 0; r < 4; ++r) {
          const size_t grow = m0 + wr * 64 + m * 16 + lm * 4 + r;
          const int gcol = n0 + wc * 64 + n * 16 + ln;
          C[grow * 2048 + gcol] = acc[m][n][r];
        }
  }
}

// ---------------------------------------------------------------- flash diff-attn
// Diagonal-paired: block pid handles Q-tiles qt=pid and qt=31-pid -> uniform
// 33 tile-iterations per block. K/V double-buffered, one barrier per iter.
// Q pre-scaled by HD^-0.5 * log2(e) => P = exp2(S); fixed-max softmax (scores
// bounded ~N(0,0.7), max < ~7 in log2 domain; f32 sums safe).
__global__ __launch_bounds__(256, 2) void flash_diff(const bf16_t* __restrict__ Q,
                                                     const bf16_t* __restrict__ K,
                                                     const bf16_t* __restrict__ Vt,
                                                     bf16_t* __restrict__ attnb,
                                                     const float* __restrict__ lamP) {
  // LDS layout (80 KB): [0,16K) Qs (overlaid by Ps after qf extraction);
  // [16K,32K) K buf0; [32K,48K) K buf1; [48K,64K) V buf0; [64K,80K) V buf1.
  __shared__ __align__(16) char smem[81920];
  bf16_t* Ps = (bf16_t*)smem;  // 4 waves x 2 sub x [16][64]

  const int tid = threadIdx.x;
  const int w = tid >> 6, lane = tid & 63;
  const int lm = lane >> 4, ln = lane & 15;
  const int h = blockIdx.y, b = blockIdx.z;
  const size_t bt0 = (size_t)b * 2048;
  const float lam = *lamP;

  auto stage_kv = [&](int buf, int k0) {
#pragma unroll
    for (int j = 0; j < 4; ++j) {
      const int inst = w * 4 + j;
      {  // K tile [64][128], RS=256B
        const int row = inst * 4 + (lane >> 4);
        const int cb = ((lane & 15) * 16) ^ ((row & 7) << 4);
        gload_lds16(K + (bt0 + k0 + row) * 2048 + h * 128 + (cb >> 1),
                    smem + 16384 + buf * 16384 + inst * 1024);
      }
      {  // Vt tile [128][64], RS=128B
        const int row = inst * 8 + (lane >> 3);
        const int cb = ((lane & 7) * 16) ^ ((row & 7) << 4);
        gload_lds16(Vt + (size_t)(h * 128 + row) * 4096 + bt0 + k0 + (cb >> 1),
                    smem + 49152 + buf * 16384 + inst * 1024);
      }
    }
  };

  for (int half = 0; half < 2; ++half) {
    const int qt = half == 0 ? (int)blockIdx.x : 31 - (int)blockIdx.x;
    const int q0 = qt * 64;

    // stage Q tile [64][128] (RS=256B) + first K/V tile into buf0
#pragma unroll
    for (int j = 0; j < 4; ++j) {
      const int inst = w * 4 + j;
      const int row = inst * 4 + (lane >> 4);
      const int cb = ((lane & 15) * 16) ^ ((row & 7) << 4);
      gload_lds16(Q + (bt0 + q0 + row) * 2048 + h * 128 + (cb >> 1),
                  smem + inst * 1024);
    }
    stage_kv(0, 0);
    asm volatile("s_waitcnt vmcnt(0)" ::: "memory");
    __syncthreads();

    bf16x8 qf[2][2];
#pragma unroll
    for (int s = 0; s < 2; ++s)
#pragma unroll
      for (int kc = 0; kc < 2; ++kc) {
        const int row = w * 16 + ln;
        int off = row * 256 + s * 128 + kc * 64 + lm * 16;
        off ^= (row & 7) << 4;
        qf[s][kc] = *(const bf16x8*)((const char*)smem + off);
      }
    __syncthreads();  // all qf reads drained before Ps overlay is written

    const f32x4 vzero = {0.f, 0.f, 0.f, 0.f};
    f32x4 acc[2][8];
    float lsum[2][4];
#pragma unroll
    for (int s = 0; s < 2; ++s) {
#pragma unroll
      for (int n = 0; n < 8; ++n) acc[s][n] = vzero;
#pragma unroll
      for (int r = 0; r < 4; ++r) lsum[s][r] = 0.f;
    }

    int cur = 0;
    for (int kt = 0; kt <= qt; ++kt) {
      // prefetch next K/V tile into the dead buffer (overlaps compute below)
      if (kt < qt) stage_kv(cur ^ 1, (kt + 1) * 64);

      const char* Ksb = (const char*)smem + 16384 + cur * 16384;
      const char* Vsb = (const char*)smem + 49152 + cur * 16384;

#pragma unroll
      for (int s = 0; s < 2; ++s) {
        f32x4 sa[4];
#pragma unroll
        for (int n = 0; n < 4; ++n) sa[n] = vzero;
        __builtin_amdgcn_s_setprio(1);
#pragma unroll
        for (int kc = 0; kc < 2; ++kc) {
#pragma unroll
          for (int n = 0; n < 4; ++n) {
            const int row = n * 16 + ln;
            int off = row * 256 + s * 128 + kc * 64 + lm * 16;
            off ^= (row & 7) << 4;
            bf16x8 kf = *(const bf16x8*)(Ksb + off);
            sa[n] = mfma_bf16(qf[s][kc], kf, sa[n]);
          }
        }
        __builtin_amdgcn_s_setprio(0);
        if (kt == qt) {  // causal mask within diagonal tile
#pragma unroll
          for (int n = 0; n < 4; ++n)
#pragma unroll
            for (int r = 0; r < 4; ++r) {
              const int kg = n * 16 + ln;
              const int qg = w * 16 + lm * 4 + r;
              if (kg > qg) sa[n][r] = -1e30f;
            }
        }
        // P = exp2(S); per-lane partial row sums only (no cross-lane here)
        bf16_t* pbase = Ps + (w * 2 + s) * 1024;
#pragma unroll
        for (int r = 0; r < 4; ++r) {
          float ps = 0.f;
#pragma unroll
          for (int n = 0; n < 4; ++n) {
            const float p = exp2f(sa[n][r]);
            sa[n][r] = p;
            ps += p;
          }
          lsum[s][r] += ps;
        }
        // write P (bf16) to per-wave scratch [16][64], RS=128B, swizzled
#pragma unroll
        for (int n = 0; n < 4; ++n)
#pragma unroll
          for (int r = 0; r < 4; ++r) {
            const int row = lm * 4 + r;
            int off = row * 128 + (n * 16 + ln) * 2;
            off ^= (row & 7) << 4;
            *(bf16_t*)((char*)pbase + off) = (bf16_t)sa[n][r];
          }
      }

      // PV for both sub-heads, V fragments read once
#pragma unroll
      for (int kc = 0; kc < 2; ++kc) {
        bf16x8 pf[2];
#pragma unroll
        for (int s = 0; s < 2; ++s) {
          int off = ln * 128 + kc * 64 + lm * 16;
          off ^= (ln & 7) << 4;
          pf[s] = *(const bf16x8*)((const char*)(Ps + (w * 2 + s) * 1024) + off);
        }
        __builtin_amdgcn_s_setprio(1);
#pragma unroll
        for (int n = 0; n < 8; ++n) {
          const int row = n * 16 + ln;
          int off = row * 128 + kc * 64 + lm * 16;
          off ^= (row & 7) << 4;
          bf16x8 vf = *(const bf16x8*)(Vsb + off);
          acc[0][n] = mfma_bf16(pf[0], vf, acc[0][n]);
          acc[1][n] = mfma_bf16(pf[1], vf, acc[1][n]);
        }
        __builtin_amdgcn_s_setprio(0);
      }

      // drain prefetch + release buf[cur] for next iteration's prefetch
      asm volatile("s_waitcnt vmcnt(0)" ::: "memory");
      __syncthreads();
      cur ^= 1;
    }

    // epilogue: finish row sums, combine, RMSNorm(128), store (registers only)
#pragma unroll
    for (int r = 0; r < 4; ++r) {
      float l0 = lsum[0][r], l1 = lsum[1][r];
#pragma unroll
      for (int d = 1; d < 16; d <<= 1) {
        l0 += __shfl_xor(l0, d);
        l1 += __shfl_xor(l1, d);
      }
      const float rl0 = 1.0f / l0;
      const float rl1 = 1.0f / l1;
      float o[8];
      float ss = 0.f;
#pragma unroll
      for (int n = 0; n < 8; ++n) {
        const float v = acc[0][n][r] * rl0 - lam * (acc[1][n][r] * rl1);
        o[n] = v;
        ss += v * v;
      }
      ss += __shfl_xor(ss, 1);
      ss += __shfl_xor(ss, 2);
      ss += __shfl_xor(ss, 4);
      ss += __shfl_xor(ss, 8);
      const float sc = rsqrtf(ss * (1.0f / 128.f) + 1e-5f) * ONE_MINUS_LAMBDA_INIT;
      const size_t grow = bt0 + q0 + w * 16 + lm * 4 + r;
#pragma unroll
      for (int n = 0; n < 8; ++n)
        attnb[grow * 2048 + h * 128 + n * 16 + ln] = (bf16_t)(o[n] * sc);
    }
  }
}

// ---------------------------------------------------------------- launch
extern "C" void kernel_launch(void* const* d_in, const int* in_sizes, int n_in,
                              void* d_out, int out_size, void* d_ws, size_t ws_size,
                              hipStream_t stream) {
  const float* x   = (const float*)d_in[0];
  const float* Wq  = (const float*)d_in[1];
  const float* Wk  = (const float*)d_in[2];
  const float* Wv  = (const float*)d_in[3];
  const float* Wo  = (const float*)d_in[4];
  const float* lq1 = (const float*)d_in[5];
  const float* lk1 = (const float*)d_in[6];
  const float* lq2 = (const float*)d_in[7];
  const float* lk2 = (const float*)d_in[8];

  char* ws = (char*)d_ws;
  // layout (bytes)
  bf16_t* xb    = (bf16_t*)(ws + 0);                 // 16 MB  [4096,2048]
  bf16_t* wqT   = (bf16_t*)(ws + 16777216);          // 8 MB
  bf16_t* wkT   = (bf16_t*)(ws + 25165824);          // 8 MB
  bf16_t* wvT   = (bf16_t*)(ws + 33554432);          // 8 MB
  bf16_t* woT   = (bf16_t*)(ws + 41943040);          // 8 MB
  bf16_t* Qb    = (bf16_t*)(ws + 50331648);          // 16 MB
  bf16_t* Kb    = (bf16_t*)(ws + 67108864);          // 16 MB
  bf16_t* Vtb   = (bf16_t*)(ws + 16777216);          // 16 MB (aliases wqT+wkT; used after their GEMMs)
  bf16_t* attnb = (bf16_t*)(ws + 0);                 // 16 MB (aliases xb; used after V GEMM)
  float*  lamP  = (float*)(ws + 83886080);

  cvt_bf16<<<4096, 256, 0, stream>>>(x, xb);
  // fold HD^-0.5 * log2(e) into Q so P = exp2(S)
  cvt_wT<<<dim3(32, 32), 256, 0, stream>>>(Wq, wqT, 0.125f * L2E);
  cvt_wT<<<dim3(32, 32), 256, 0, stream>>>(Wk, wkT, 1.0f);
  cvt_wT<<<dim3(32, 32), 256, 0, stream>>>(Wv, wvT, 1.0f);
  cvt_wT<<<dim3(32, 32), 256, 0, stream>>>(Wo, woT, 1.0f);
  lam_kernel<<<1, 64, 0, stream>>>(lq1, lk1, lq2, lk2, lamP);

  gemm_bt<0><<<dim3(32, 16), 256, 0, stream>>>(xb, wqT, (void*)Qb);
  gemm_bt<0><<<dim3(32, 16), 256, 0, stream>>>(xb, wkT, (void*)Kb);
  gemm_bt<1><<<dim3(32, 16), 256, 0, stream>>>(xb, wvT, (void*)Vtb);  // V^T out

  flash_diff<<<dim3(16, 16, 2), 256, 0, stream>>>(Qb, Kb, Vtb, attnb, lamP);

  gemm_bt<2><<<dim3(32, 16), 256, 0, stream>>>(attnb, woT, d_out);
}